// Round 1
// baseline (148.857 us; speedup 1.0000x reference)
//
#include <hip/hip_runtime.h>
#include <math.h>

#define NW   12
#define DIM  4096
#define TPB  256

// insert a 0 bit at position b
__device__ __forceinline__ int ins0(int v, int b) {
    return ((v >> b) << (b + 1)) | (v & ((1 << b) - 1));
}

// (a,b) <- M (a,b), complex 2x2
__device__ __forceinline__ void cgate(float2& a, float2& b,
        const float2 m00, const float2 m01, const float2 m10, const float2 m11) {
    float2 na, nb;
    na.x = fmaf(m00.x, a.x, fmaf(-m00.y, a.y, fmaf(m01.x, b.x, -m01.y * b.y)));
    na.y = fmaf(m00.x, a.y, fmaf( m00.y, a.x, fmaf(m01.x, b.y,  m01.y * b.x)));
    nb.x = fmaf(m10.x, a.x, fmaf(-m10.y, a.y, fmaf(m11.x, b.x, -m11.y * b.y)));
    nb.y = fmaf(m10.x, a.y, fmaf( m10.y, a.x, fmaf(m11.x, b.y,  m11.y * b.x)));
    a = na; b = nb;
}

// apply gate M to bits bh and bl (bh>bl) of the whole state, one sweep.
// quads (both bits = 0 base) partitioned: q = tid + 256*k, k=0..3 (1024 quads).
__device__ __forceinline__ void sweep_pair(float2* psi, int tid, int bh, int bl,
        const float2 m00, const float2 m01, const float2 m10, const float2 m11) {
#pragma unroll
    for (int k = 0; k < 4; ++k) {
        int q   = tid + TPB * k;
        int i00 = ins0(ins0(q, bl), bh);
        int i01 = i00 | (1 << bl);
        int i10 = i00 | (1 << bh);
        int i11 = i10 | (1 << bl);
        float2 v00 = psi[i00], v01 = psi[i01], v10 = psi[i10], v11 = psi[i11];
        // gate on low bit
        cgate(v00, v01, m00, m01, m10, m11);
        cgate(v10, v11, m00, m01, m10, m11);
        // gate on high bit
        cgate(v00, v10, m00, m01, m10, m11);
        cgate(v01, v11, m00, m01, m10, m11);
        psi[i00] = v00; psi[i01] = v01; psi[i10] = v10; psi[i11] = v11;
    }
    __syncthreads();
}

__global__ __launch_bounds__(TPB, 4)
void qmnist_kernel(const float* __restrict__ x,  const float* __restrict__ W1,
                   const float* __restrict__ b1, const float* __restrict__ ryp,
                   const float* __restrict__ rzp, const float* __restrict__ W2,
                   const float* __restrict__ b2, float* __restrict__ out) {
    __shared__ float2 psi[DIM];
    __shared__ float  wred[4 * NW];
    __shared__ float  encc[NW], encs[NW];
    __shared__ float  zfin[NW];

    const int tid  = threadIdx.x;
    const int blk  = blockIdx.x;
    const int lane = tid & 63;
    const int wave = tid >> 6;

    // ---------------- phase 0: feat = x[blk] @ W1^T + b1 -> encoding angles
    float acc[NW];
#pragma unroll
    for (int w = 0; w < NW; ++w) acc[w] = 0.f;
    const float* xrow = x + (size_t)blk * 784;
    for (int j = tid; j < 784; j += TPB) {
        float xv = xrow[j];
#pragma unroll
        for (int w = 0; w < NW; ++w)
            acc[w] = fmaf(xv, W1[w * 784 + j], acc[w]);
    }
#pragma unroll
    for (int w = 0; w < NW; ++w) {
        float v = acc[w];
        v += __shfl_down(v, 32);
        v += __shfl_down(v, 16);
        v += __shfl_down(v, 8);
        v += __shfl_down(v, 4);
        v += __shfl_down(v, 2);
        v += __shfl_down(v, 1);
        if (lane == 0) wred[wave * NW + w] = v;
    }
    __syncthreads();
    if (tid < NW) {
        float feat = wred[tid] + wred[NW + tid] + wred[2 * NW + tid] + wred[3 * NW + tid] + b1[tid];
        float a = tanhf(feat) * 3.14159265358979323846f;
        float h = 0.5f * a;
        encc[tid] = cosf(h);
        encs[tid] = sinf(h);
    }
    __syncthreads();

    // ---------------- init product state.  index i = k*256 + tid.
    // bit b of i corresponds to wire (11-b).  bits 0..7 = tid, bits 8..11 = k.
    float hi = 1.f;
#pragma unroll
    for (int b = 0; b < 8; ++b) {
        int w = 11 - b;
        hi *= ((tid >> b) & 1) ? encs[w] : encc[w];
    }
#pragma unroll
    for (int k = 0; k < 16; ++k) {
        float f = hi;
        f *= (k & 1) ? encs[3] : encc[3];   // bit 8  -> wire 3
        f *= (k & 2) ? encs[2] : encc[2];   // bit 9  -> wire 2
        f *= (k & 4) ? encs[1] : encc[1];   // bit 10 -> wire 1
        f *= (k & 8) ? encs[0] : encc[0];   // bit 11 -> wire 0
        psi[k * TPB + tid] = make_float2(f, 0.f);
    }
    __syncthreads();

    // ---------------- fused variational gate  M = RZ(rz) * RY(ry), same on all wires
    const float ry = ryp[0], rz = rzp[0];
    const float c  = cosf(0.5f * ry), s  = sinf(0.5f * ry);
    const float zc = cosf(0.5f * rz), zs = sinf(0.5f * rz);
    const float2 m00 = make_float2( c * zc, -c * zs);
    const float2 m01 = make_float2(-s * zc,  s * zs);
    const float2 m10 = make_float2( s * zc,  s * zs);
    const float2 m11 = make_float2( c * zc,  c * zs);

    for (int layer = 0; layer < 3; ++layer) {
        // 12 single-qubit gates as 6 two-bit sweeps (pairs chosen for LDS bank friendliness)
        sweep_pair(psi, tid,  8, 0, m00, m01, m10, m11);
        sweep_pair(psi, tid,  9, 1, m00, m01, m10, m11);
        sweep_pair(psi, tid, 10, 2, m00, m01, m10, m11);
        sweep_pair(psi, tid, 11, 3, m00, m01, m10, m11);
        sweep_pair(psi, tid,  6, 4, m00, m01, m10, m11);
        sweep_pair(psi, tid,  7, 5, m00, m01, m10, m11);
        // CNOT staircase (w=0..10) composes to: psi_new[y] = psi_old[y ^ (y>>1)]
        float2 tmp[16];
#pragma unroll
        for (int k = 0; k < 16; ++k) {
            int y = k * TPB + tid;
            tmp[k] = psi[y ^ (y >> 1)];
        }
        __syncthreads();
#pragma unroll
        for (int k = 0; k < 16; ++k)
            psi[k * TPB + tid] = tmp[k];
        __syncthreads();
    }

    // ---------------- measure <Z_w> for all wires
    float t_total = 0.f, s3 = 0.f, s2 = 0.f, s1 = 0.f, s0 = 0.f;
#pragma unroll
    for (int k = 0; k < 16; ++k) {
        float2 v = psi[k * TPB + tid];
        float pp = fmaf(v.x, v.x, v.y * v.y);
        t_total += pp;
        if (k & 1) s3 += pp;   // bit 8  -> wire 3
        if (k & 2) s2 += pp;   // bit 9  -> wire 2
        if (k & 4) s1 += pp;   // bit 10 -> wire 1
        if (k & 8) s0 += pp;   // bit 11 -> wire 0
    }
    float contrib[NW];
    contrib[3] = t_total - 2.f * s3;
    contrib[2] = t_total - 2.f * s2;
    contrib[1] = t_total - 2.f * s1;
    contrib[0] = t_total - 2.f * s0;
#pragma unroll
    for (int b = 0; b < 8; ++b) {
        int w = 11 - b;                      // wires 11..4 from tid bits 0..7
        contrib[w] = ((tid >> b) & 1) ? -t_total : t_total;
    }
#pragma unroll
    for (int w = 0; w < NW; ++w) {
        float v = contrib[w];
        v += __shfl_down(v, 32);
        v += __shfl_down(v, 16);
        v += __shfl_down(v, 8);
        v += __shfl_down(v, 4);
        v += __shfl_down(v, 2);
        v += __shfl_down(v, 1);
        if (lane == 0) wred[wave * NW + w] = v;
    }
    __syncthreads();
    if (tid < NW)
        zfin[tid] = wred[tid] + wred[NW + tid] + wred[2 * NW + tid] + wred[3 * NW + tid];
    __syncthreads();

    // ---------------- head: out = z @ W2^T + b2
    if (tid < 10) {
        float o = b2[tid];
#pragma unroll
        for (int w = 0; w < NW; ++w)
            o = fmaf(zfin[w], W2[tid * NW + w], o);
        out[(size_t)blk * 10 + tid] = o;
    }
}

extern "C" void kernel_launch(void* const* d_in, const int* in_sizes, int n_in,
                              void* d_out, int out_size, void* d_ws, size_t ws_size,
                              hipStream_t stream) {
    const float* x   = (const float*)d_in[0];
    const float* W1  = (const float*)d_in[1];
    const float* b1  = (const float*)d_in[2];
    const float* ry  = (const float*)d_in[3];
    const float* rz  = (const float*)d_in[4];
    const float* W2  = (const float*)d_in[5];
    const float* b2  = (const float*)d_in[6];
    float* out = (float*)d_out;

    const int batch = in_sizes[0] / 784;   // 2048
    qmnist_kernel<<<batch, TPB, 0, stream>>>(x, W1, b1, ry, rz, W2, b2, out);
}